// Round 18
// baseline (207.868 us; speedup 1.0000x reference)
//
#include <hip/hip_runtime.h>
#include <math.h>

#define NB 4
#define NT 2048
#define NE 1024
#define NH 16
#define ND 64
#define NF 32

typedef _Float16 half8 __attribute__((ext_vector_type(8)));
typedef __fp16 fp16x2 __attribute__((ext_vector_type(2)));
typedef unsigned int uint2v __attribute__((ext_vector_type(2)));
typedef unsigned int uint4v __attribute__((ext_vector_type(4)));
typedef float f32x4 __attribute__((ext_vector_type(4)));
typedef float f32x16 __attribute__((ext_vector_type(16)));
#define MFMA16(a, b, c) __builtin_amdgcn_mfma_f32_16x16x32_f16(a, b, c, 0, 0, 0)
#define MFMA32(a, b, c) __builtin_amdgcn_mfma_f32_32x32x16_f16(a, b, c, 0, 0, 0)

// global -> LDS direct DMA, 16B per lane; LDS dest = wave-uniform base + lane*16
#define GLOAD_LDS16(gsrc, ldsbase)                                            \
    __builtin_amdgcn_global_load_lds(                                         \
        (const __attribute__((address_space(1))) void*)(gsrc),                \
        (__attribute__((address_space(3))) void*)(ldsbase), 16, 0, 0)

__device__ __forceinline__ float fast_exp2(float x) {
    float r;
    asm volatile("v_exp_f32 %0, %1" : "=v"(r) : "v"(x));
    return r;
}

// ============================================================================
// Kernel 0: fp32 -> fp16 conversion of X, Wi, Wo (one pass, grid-stride).
// ============================================================================
__global__ __launch_bounds__(256)
void cvt_kernel(const float* __restrict__ X, const float* __restrict__ Wi,
                const float* __restrict__ Wo,
                _Float16* __restrict__ Xh, _Float16* __restrict__ Wih,
                _Float16* __restrict__ Woh)
{
    const size_t NX = (size_t)8388608, NWI = 3145728, NWO = 1048576;
    const size_t TOT = (NX + NWI + NWO) / 8;   // half8 groups
    for (size_t gidx = (size_t)blockIdx.x*256 + threadIdx.x; gidx < TOT;
         gidx += (size_t)gridDim.x*256) {
        size_t i = gidx*8;
        const float* src; _Float16* dst; size_t off;
        if (i < NX)            { src = X;  dst = Xh;  off = i; }
        else if (i < NX + NWI) { src = Wi; dst = Wih; off = i - NX; }
        else                   { src = Wo; dst = Woh; off = i - NX - NWI; }
        float4 a = *(const float4*)(src + off);
        float4 b = *(const float4*)(src + off + 4);
        half8 h;
        h[0]=(_Float16)a.x; h[1]=(_Float16)a.y; h[2]=(_Float16)a.z; h[3]=(_Float16)a.w;
        h[4]=(_Float16)b.x; h[5]=(_Float16)b.y; h[6]=(_Float16)b.z; h[7]=(_Float16)b.w;
        *(half8*)(dst + off) = h;
    }
}

// ============================================================================
// Kernel 1: fp16 MFMA GEMM  C = Xh * Wih^T (+bias), fused rotary epilogue.
// R15 structure: 2-phase double-buffered global_load_lds pipeline; ds_read
// current fragments FIRST, then issue next-tile DMA, then MFMA; one
// __syncthreads per K-step. Q pre-scaled by (1/8)*log2(e).
// ============================================================================
__global__ __launch_bounds__(256)
void qkv_mfma_kernel(const _Float16* __restrict__ Ah,
                     const _Float16* __restrict__ Bh,
                     const float* __restrict__ bias,
                     const float* __restrict__ pos,
                     const float* __restrict__ freqs,
                     _Float16* __restrict__ Qh,
                     _Float16* __restrict__ Kh,
                     _Float16* __restrict__ Vh)
{
    __shared__ _Float16 Ash[2][128*32];
    __shared__ _Float16 Bsh[2][128*32];

    const int tid = threadIdx.x;
    const int wid = tid >> 6, lane = tid & 63;
    const int ln = lane & 15, g = lane >> 4;
    const int wrow = wid >> 1, wcol = wid & 1;
    const int m0 = blockIdx.x * 128, n0 = blockIdx.y * 128;

    // per-lane swizzled global source; linear LDS dest (tid*16B)
    const int r0 = tid >> 2, s0 = tid & 3;
    const int k8 = s0 ^ ((r0 >> 1) & 3);
    const _Float16* gA0 = Ah + (size_t)(m0 + r0)      * NE + k8*8;
    const _Float16* gA1 = Ah + (size_t)(m0 + r0 + 64) * NE + k8*8;
    const _Float16* gB0 = Bh + (size_t)(n0 + r0)      * NE + k8*8;
    const _Float16* gB1 = Bh + (size_t)(n0 + r0 + 64) * NE + k8*8;

    const int wb = (tid & ~63) * 8;            // wave-uniform LDS base (elems)
    const int xr = g ^ ((ln >> 1) & 3);

    f32x4 acc[4][4];
    #pragma unroll
    for (int i = 0; i < 4; ++i)
        #pragma unroll
        for (int j = 0; j < 4; ++j) acc[i][j] = (f32x4){0.f,0.f,0.f,0.f};

    // prologue: stage tile 0 into buf 0
    GLOAD_LDS16(gA0, Ash[0] + wb);
    GLOAD_LDS16(gA1, Ash[0] + wb + 256*8);
    GLOAD_LDS16(gB0, Bsh[0] + wb);
    GLOAD_LDS16(gB1, Bsh[0] + wb + 256*8);
    __syncthreads();

    for (int kt = 0; kt < NE; kt += 32) {
        const int cur = (kt >> 5) & 1;
        const int nxt = cur ^ 1;
        const int kn = kt + 32;
        // ds_read current fragments FIRST (starts the lgkm chain early)
        half8 af[4], bf[4];
        #pragma unroll
        for (int mf = 0; mf < 4; ++mf)
            af[mf] = *(const half8*)&Ash[cur][(wrow*64 + mf*16 + ln)*32 + xr*8];
        #pragma unroll
        for (int nf = 0; nf < 4; ++nf)
            bf[nf] = *(const half8*)&Bsh[cur][(wcol*64 + nf*16 + ln)*32 + xr*8];
        // then issue next-tile DMA (overlaps the ds_read latency)
        if (kn < NE) {
            GLOAD_LDS16(gA0 + kn, Ash[nxt] + wb);
            GLOAD_LDS16(gA1 + kn, Ash[nxt] + wb + 256*8);
            GLOAD_LDS16(gB0 + kn, Bsh[nxt] + wb);
            GLOAD_LDS16(gB1 + kn, Bsh[nxt] + wb + 256*8);
        }
        __builtin_amdgcn_s_setprio(1);
        #pragma unroll
        for (int mf = 0; mf < 4; ++mf)
            #pragma unroll
            for (int nf = 0; nf < 4; ++nf)
                acc[mf][nf] = MFMA16(af[mf], bf[nf], acc[mf][nf]);
        __builtin_amdgcn_s_setprio(0);
        __syncthreads();                       // drains next-tile loads too
    }

    const int sec = n0 >> 10;
    _Float16* dst = (sec == 0) ? Qh : (sec == 1) ? Kh : Vh;

    float cb[4], fx[4], fy[4], fz[4];
    int hh[4], dd[4];
    #pragma unroll
    for (int nf = 0; nf < 4; ++nf) {
        const int col = n0 + wcol*64 + nf*16 + ln;
        cb[nf] = bias[col];
        const int e = col & 1023;
        hh[nf] = e >> 6; dd[nf] = e & 63;
        if (sec != 2) {
            const float* fq = freqs + ((size_t)hh[nf]*NF + (dd[nf] >> 1))*3;
            fx[nf] = fq[0]; fy[nf] = fq[1]; fz[nf] = fq[2];
        }
    }
    const float sgn = (ln & 1) ? 1.0f : -1.0f;
    const float qs  = (sec == 0) ? 0.125f * 1.4426950408889634f : 1.0f;

    #pragma unroll
    for (int mf = 0; mf < 4; ++mf) {
        #pragma unroll
        for (int r = 0; r < 4; ++r) {
            const int m = m0 + wrow*64 + mf*16 + g*4 + r;
            const int b = m >> 11, t = m & 2047;
            if (sec == 2) {
                #pragma unroll
                for (int nf = 0; nf < 4; ++nf)
                    dst[((size_t)(b*NH + hh[nf])*NT + t)*ND + dd[nf]] =
                        (_Float16)(acc[mf][nf][r] + cb[nf]);
            } else {
                const float px = pos[(size_t)m*3 + 0];
                const float py = pos[(size_t)m*3 + 1];
                const float pz = pos[(size_t)m*3 + 2];
                #pragma unroll
                for (int nf = 0; nf < 4; ++nf) {
                    const float x  = acc[mf][nf][r] + cb[nf];
                    const float xo = __shfl_xor(x, 1);
                    const float ang = px*fx[nf] + py*fy[nf] + pz*fz[nf];
                    float sn, cs;
                    __sincosf(ang, &sn, &cs);
                    const float out = (x*cs + sgn*xo*sn) * qs;
                    dst[((size_t)(b*NH + hh[nf])*NT + t)*ND + dd[nf]] = (_Float16)out;
                }
            }
        }
    }
}

// ============================================================================
// Kernel 2: fp16 flash attention, 32x32x16 MFMA, swapped QK^T. (R13 exactly)
// ============================================================================
__global__ __launch_bounds__(512, 4)
void attn_mfma_kernel(const _Float16* __restrict__ Qg, const _Float16* __restrict__ Kg,
                      const _Float16* __restrict__ Vg, _Float16* __restrict__ Og)
{
    __shared__ _Float16 Ks[2][64][70];      // [buf][key][d]
    __shared__ _Float16 VsT[2][64][70];     // [buf][d][key]

    const int tid  = threadIdx.x;
    const int wid  = tid >> 6;
    const int lane = tid & 63;
    const int m31  = lane & 31;
    const int hi   = lane >> 5;
    const int bh   = blockIdx.x;
    const int qt   = blockIdx.y;
    const int b = bh >> 4, h = bh & 15;
    const _Float16* Qp = Qg + (size_t)bh * NT * ND;
    const _Float16* Kp = Kg + (size_t)bh * NT * ND;
    const _Float16* Vp = Vg + (size_t)bh * NT * ND;

    const int qrow_g = qt*256 + wid*32 + m31;

    half8 qfr[4];
    #pragma unroll
    for (int c = 0; c < 4; ++c)
        qfr[c] = *(const half8*)(Qp + (size_t)qrow_g*ND + 16*c + 8*hi);

    f32x16 o0, o1;
    #pragma unroll
    for (int e = 0; e < 16; ++e) { o0[e] = 0.f; o1[e] = 0.f; }
    float m_i = 8.0f, l_i = 0.0f;    // static bound; exact slow path guards it

    // staging geometry (512 threads)
    const int sr  = tid >> 3;            // K: key row 0..63
    const int sc0 = (tid & 7) * 8;       // K: d col base
    const int dp  = tid & 31;            // V: dword index (d = 2dp, 2dp+1)
    const int wv  = tid >> 5;            // V: key group 0..15 (4 keys each)
    const _Float16* kbase = Kp + (size_t)sr*ND + sc0;
    const _Float16* vbase = Vp + (size_t)(wv*4)*ND + 2*dp;

    half8 kv;
    unsigned int vr[4];

    #define LOADREGS(off)  do {                                              \
        kv = *(const half8*)(kbase + (size_t)(off)*ND);                      \
        _Pragma("unroll")                                                    \
        for (int j = 0; j < 4; ++j)                                          \
            vr[j] = *(const unsigned int*)(vbase + (size_t)((off) + j)*ND);  \
    } while (0)

    #define STOREBUF(bf)  do {                                               \
        *(half8*)&Ks[bf][sr][sc0] = kv;                                      \
        uint2v lod, hid;                                                     \
        lod[0] = __builtin_amdgcn_perm(vr[1], vr[0], 0x05040100u);           \
        lod[1] = __builtin_amdgcn_perm(vr[3], vr[2], 0x05040100u);           \
        hid[0] = __builtin_amdgcn_perm(vr[1], vr[0], 0x07060302u);           \
        hid[1] = __builtin_amdgcn_perm(vr[3], vr[2], 0x07060302u);           \
        *(uint2v*)&VsT[bf][2*dp][wv*4]     = lod;                            \
        *(uint2v*)&VsT[bf][2*dp + 1][wv*4] = hid;                            \
    } while (0)

    LOADREGS(0);
    STOREBUF(0);
    LOADREGS(64);

    for (int t = 0; t < 32; ++t) {
        const int cur = t & 1;
        __syncthreads();
        if (t < 31) STOREBUF(cur ^ 1);          // regs hold tile t+1
        if (t < 30) LOADREGS((t + 2) * 64);     // prefetch tile t+2

        // ---- S' = K.Q^T - m  (C initialized to -m_i) ----
        f32x16 st0, st1;
        const float mneg = -m_i;
        #pragma unroll
        for (int e = 0; e < 16; ++e) { st0[e] = mneg; st1[e] = mneg; }

        __builtin_amdgcn_s_setprio(1);
        #pragma unroll
        for (int c = 0; c < 4; ++c) {
            half8 kf0 = *(const half8*)&Ks[cur][m31][16*c + 8*hi];
            half8 kf1 = *(const half8*)&Ks[cur][32 + m31][16*c + 8*hi];
            st0 = MFMA32(kf0, qfr[c], st0);
            st1 = MFMA32(kf1, qfr[c], st1);
        }
        __builtin_amdgcn_s_setprio(0);

        // ---- p = exp2(s'), pack, fdot2 sums (no max tree on fast path) ----
        const fp16x2 ones2 = {(__fp16)1.0f, (__fp16)1.0f};
        unsigned int pku0[8], pku1[8];
        float rsA = 0.f, rsB = 0.f;
        #pragma unroll
        for (int jx = 0; jx < 8; ++jx) {
            const float pa0 = fast_exp2(st0[2*jx]);
            const float pa1 = fast_exp2(st0[2*jx + 1]);
            const float pb0 = fast_exp2(st1[2*jx]);
            const float pb1 = fast_exp2(st1[2*jx + 1]);
            const fp16x2 h2a = __builtin_amdgcn_cvt_pkrtz(pa0, pa1);
            const fp16x2 h2b = __builtin_amdgcn_cvt_pkrtz(pb0, pb1);
            pku0[jx] = __builtin_bit_cast(unsigned int, h2a);
            pku1[jx] = __builtin_bit_cast(unsigned int, h2b);
            rsA = __builtin_amdgcn_fdot2(h2a, ones2, rsA, false);
            rsB = __builtin_amdgcn_fdot2(h2b, ones2, rsB, false);
        }
        float rs = rsA + rsB;
        rs += __shfl_xor(rs, 32);

        // ---- slow path: row sum blew the bound (rs >= pmax, conservative) ----
        if (__any(rs > 256.0f)) {
            float smax = st0[0];
            #pragma unroll
            for (int e = 1; e < 16; ++e) smax = fmaxf(smax, st0[e]);
            #pragma unroll
            for (int e = 0; e < 16; ++e) smax = fmaxf(smax, st1[e]);
            smax = fmaxf(smax, __shfl_xor(smax, 32));
            const float delta = (smax > 0.0f) ? smax : 0.0f;
            const float alpha = fast_exp2(-delta);
            m_i += delta;
            l_i *= alpha;
            rs  *= alpha;
            fp16x2 am; am[0] = (__fp16)alpha; am[1] = (__fp16)alpha;
            #pragma unroll
            for (int jx = 0; jx < 8; ++jx) {
                fp16x2 p0v = __builtin_bit_cast(fp16x2, pku0[jx]) * am;
                fp16x2 p1v = __builtin_bit_cast(fp16x2, pku1[jx]) * am;
                pku0[jx] = __builtin_bit_cast(unsigned int, p0v);
                pku1[jx] = __builtin_bit_cast(unsigned int, p1v);
            }
            #pragma unroll
            for (int reg = 0; reg < 16; ++reg) {
                const int qr = (reg & 3) + 8*(reg >> 2) + 4*hi;
                const float a = __shfl(alpha, qr);
                o0[reg] *= a; o1[reg] *= a;
            }
        }
        l_i += rs;

        // ---- O += P . V : permlane32_swap assembles the A-frag ----
        __builtin_amdgcn_s_setprio(1);
        #pragma unroll
        for (int kc = 0; kc < 4; ++kc) {
            const unsigned int a0 = (kc < 2) ? pku0[4*(kc & 1) + 0] : pku1[4*(kc & 1) + 0];
            const unsigned int a1 = (kc < 2) ? pku0[4*(kc & 1) + 1] : pku1[4*(kc & 1) + 1];
            const unsigned int b0 = (kc < 2) ? pku0[4*(kc & 1) + 2] : pku1[4*(kc & 1) + 2];
            const unsigned int b1 = (kc < 2) ? pku0[4*(kc & 1) + 3] : pku1[4*(kc & 1) + 3];
            uint2v rpa = __builtin_amdgcn_permlane32_swap(a0, b0, false, false);
            uint2v rpb = __builtin_amdgcn_permlane32_swap(a1, b1, false, false);
            uint4v u;
            u[0] = rpa[0]; u[1] = rpb[0]; u[2] = rpa[1]; u[3] = rpb[1];
            const half8 pa = __builtin_bit_cast(half8, u);
            const half8 vb0 = *(const half8*)&VsT[cur][m31][16*kc + 8*hi];
            const half8 vb1 = *(const half8*)&VsT[cur][32 + m31][16*kc + 8*hi];
            o0 = MFMA32(pa, vb0, o0);
            o1 = MFMA32(pa, vb1, o1);
        }
        __builtin_amdgcn_s_setprio(0);
    }

    // ---- epilogue: normalize (l redistributed to o-row layout), write ----
    #pragma unroll
    for (int reg = 0; reg < 16; ++reg) {
        const int qr = (reg & 3) + 8*(reg >> 2) + 4*hi;
        const float lq  = __shfl(l_i, qr);
        const float inv = 1.0f / lq;
        const int qg = qt*256 + wid*32 + qr;
        _Float16* dstp = Og + ((size_t)b*NT + qg)*NE + h*ND;
        dstp[m31]      = (_Float16)(o0[reg] * inv);
        dstp[32 + m31] = (_Float16)(o1[reg] * inv);
    }
    #undef LOADREGS
    #undef STOREBUF
}

// ============================================================================
// Kernel 3: fp16 MFMA out-projection: out(f32) = Oh * Woh^T + bias. (R15)
// ============================================================================
__global__ __launch_bounds__(256)
void out_proj_mfma_kernel(const _Float16* __restrict__ Ah,
                          const _Float16* __restrict__ Bh,
                          const float* __restrict__ bias,
                          float* __restrict__ out)
{
    __shared__ _Float16 Ash[2][128*32];
    __shared__ _Float16 Bsh[2][128*32];

    const int tid = threadIdx.x;
    const int wid = tid >> 6, lane = tid & 63;
    const int ln = lane & 15, g = lane >> 4;
    const int wrow = wid >> 1, wcol = wid & 1;
    const int m0 = blockIdx.x * 128, n0 = blockIdx.y * 128;

    const int r0 = tid >> 2, s0 = tid & 3;
    const int k8 = s0 ^ ((r0 >> 1) & 3);
    const _Float16* gA0 = Ah + (size_t)(m0 + r0)      * NE + k8*8;
    const _Float16* gA1 = Ah + (size_t)(m0 + r0 + 64) * NE + k8*8;
    const _Float16* gB0 = Bh + (size_t)(n0 + r0)      * NE + k8*8;
    const _Float16* gB1 = Bh + (size_t)(n0 + r0 + 64) * NE + k8*8;

    const int wb = (tid & ~63) * 8;
    const int xr = g ^ ((ln >> 1) & 3);

    f32x4 acc[4][4];
    #pragma unroll
    for (int i = 0; i < 4; ++i)
        #pragma unroll
        for (int j = 0; j < 4; ++j) acc[i][j] = (f32x4){0.f,0.f,0.f,0.f};

    GLOAD_LDS16(gA0, Ash[0] + wb);
    GLOAD_LDS16(gA1, Ash[0] + wb + 256*8);
    GLOAD_LDS16(gB0, Bsh[0] + wb);
    GLOAD_LDS16(gB1, Bsh[0] + wb + 256*8);
    __syncthreads();

    for (int kt = 0; kt < NE; kt += 32) {
        const int cur = (kt >> 5) & 1;
        const int nxt = cur ^ 1;
        const int kn = kt + 32;
        half8 af[4], bf[4];
        #pragma unroll
        for (int mf = 0; mf < 4; ++mf)
            af[mf] = *(const half8*)&Ash[cur][(wrow*64 + mf*16 + ln)*32 + xr*8];
        #pragma unroll
        for (int nf = 0; nf < 4; ++nf)
            bf[nf] = *(const half8*)&Bsh[cur][(wcol*64 + nf*16 + ln)*32 + xr*8];
        if (kn < NE) {
            GLOAD_LDS16(gA0 + kn, Ash[nxt] + wb);
            GLOAD_LDS16(gA1 + kn, Ash[nxt] + wb + 256*8);
            GLOAD_LDS16(gB0 + kn, Bsh[nxt] + wb);
            GLOAD_LDS16(gB1 + kn, Bsh[nxt] + wb + 256*8);
        }
        __builtin_amdgcn_s_setprio(1);
        #pragma unroll
        for (int mf = 0; mf < 4; ++mf)
            #pragma unroll
            for (int nf = 0; nf < 4; ++nf)
                acc[mf][nf] = MFMA16(af[mf], bf[nf], acc[mf][nf]);
        __builtin_amdgcn_s_setprio(0);
        __syncthreads();
    }

    float cb[4];
    #pragma unroll
    for (int nf = 0; nf < 4; ++nf) cb[nf] = bias[n0 + wcol*64 + nf*16 + ln];

    #pragma unroll
    for (int mf = 0; mf < 4; ++mf)
        #pragma unroll
        for (int r = 0; r < 4; ++r) {
            const int m = m0 + wrow*64 + mf*16 + g*4 + r;
            #pragma unroll
            for (int nf = 0; nf < 4; ++nf)
                out[(size_t)m*NE + n0 + wcol*64 + nf*16 + ln] = acc[mf][nf][r] + cb[nf];
        }
}

extern "C" void kernel_launch(void* const* d_in, const int* in_sizes, int n_in,
                              void* d_out, int out_size, void* d_ws, size_t ws_size,
                              hipStream_t stream)
{
    const float* X   = (const float*)d_in[0];
    const float* pos = (const float*)d_in[1];
    const float* Wi  = (const float*)d_in[2];
    const float* bi  = (const float*)d_in[3];
    const float* Wo  = (const float*)d_in[4];
    const float* bo  = (const float*)d_in[5];
    const float* fr  = (const float*)d_in[6];
    float* out = (float*)d_out;

    _Float16* Xh  = (_Float16*)d_ws;            // 8388608
    _Float16* Wih = Xh  + 8388608;              // 3145728
    _Float16* Woh = Wih + 3145728;              // 1048576
    _Float16* Qh  = Woh + 1048576;              // 8388608
    _Float16* Kh  = Qh  + 8388608;
    _Float16* Vh  = Kh  + 8388608;
    _Float16* Oh  = Vh  + 8388608;

    cvt_kernel          <<<3072, 256, 0, stream>>>(X, Wi, Wo, Xh, Wih, Woh);
    qkv_mfma_kernel     <<<dim3(64, 24), 256, 0, stream>>>(Xh, Wih, bi, pos, fr, Qh, Kh, Vh);
    attn_mfma_kernel    <<<dim3(64, 8), 512, 0, stream>>>(Qh, Kh, Vh, Oh);
    out_proj_mfma_kernel<<<dim3(64, 8),  256, 0, stream>>>(Oh, Woh, bo, out);
}

// Round 19
// 207.346 us; speedup vs baseline: 1.0025x; 1.0025x over previous
//
#include <hip/hip_runtime.h>
#include <math.h>

#define NB 4
#define NT 2048
#define NE 1024
#define NH 16
#define ND 64
#define NF 32

typedef _Float16 half8 __attribute__((ext_vector_type(8)));
typedef __fp16 fp16x2 __attribute__((ext_vector_type(2)));
typedef unsigned int uint2v __attribute__((ext_vector_type(2)));
typedef unsigned int uint4v __attribute__((ext_vector_type(4)));
typedef float f32x4 __attribute__((ext_vector_type(4)));
typedef float f32x16 __attribute__((ext_vector_type(16)));
#define MFMA16(a, b, c) __builtin_amdgcn_mfma_f32_16x16x32_f16(a, b, c, 0, 0, 0)
#define MFMA32(a, b, c) __builtin_amdgcn_mfma_f32_32x32x16_f16(a, b, c, 0, 0, 0)

// global -> LDS direct DMA, 16B per lane; LDS dest = wave-uniform base + lane*16
#define GLOAD_LDS16(gsrc, ldsbase)                                            \
    __builtin_amdgcn_global_load_lds(                                         \
        (const __attribute__((address_space(1))) void*)(gsrc),                \
        (__attribute__((address_space(3))) void*)(ldsbase), 16, 0, 0)

__device__ __forceinline__ float fast_exp2(float x) {
    float r;
    asm volatile("v_exp_f32 %0, %1" : "=v"(r) : "v"(x));
    return r;
}

// ============================================================================
// Kernel 0: fp32 -> fp16 conversion of X, Wi, Wo (one pass, grid-stride).
// ============================================================================
__global__ __launch_bounds__(256)
void cvt_kernel(const float* __restrict__ X, const float* __restrict__ Wi,
                const float* __restrict__ Wo,
                _Float16* __restrict__ Xh, _Float16* __restrict__ Wih,
                _Float16* __restrict__ Woh)
{
    const size_t NX = (size_t)8388608, NWI = 3145728, NWO = 1048576;
    const size_t TOT = (NX + NWI + NWO) / 8;   // half8 groups
    for (size_t gidx = (size_t)blockIdx.x*256 + threadIdx.x; gidx < TOT;
         gidx += (size_t)gridDim.x*256) {
        size_t i = gidx*8;
        const float* src; _Float16* dst; size_t off;
        if (i < NX)            { src = X;  dst = Xh;  off = i; }
        else if (i < NX + NWI) { src = Wi; dst = Wih; off = i - NX; }
        else                   { src = Wo; dst = Woh; off = i - NX - NWI; }
        float4 a = *(const float4*)(src + off);
        float4 b = *(const float4*)(src + off + 4);
        half8 h;
        h[0]=(_Float16)a.x; h[1]=(_Float16)a.y; h[2]=(_Float16)a.z; h[3]=(_Float16)a.w;
        h[4]=(_Float16)b.x; h[5]=(_Float16)b.y; h[6]=(_Float16)b.z; h[7]=(_Float16)b.w;
        *(half8*)(dst + off) = h;
    }
}

// ============================================================================
// Kernel 1: fp16 MFMA GEMM  C = Xh * Wih^T (+bias), fused rotary epilogue.
// R15 structure: 2-phase double-buffered global_load_lds pipeline; ds_read
// current fragments FIRST, then issue next-tile DMA, then MFMA; one
// __syncthreads per K-step. Q pre-scaled by (1/8)*log2(e).
// ============================================================================
__global__ __launch_bounds__(256)
void qkv_mfma_kernel(const _Float16* __restrict__ Ah,
                     const _Float16* __restrict__ Bh,
                     const float* __restrict__ bias,
                     const float* __restrict__ pos,
                     const float* __restrict__ freqs,
                     _Float16* __restrict__ Qh,
                     _Float16* __restrict__ Kh,
                     _Float16* __restrict__ Vh)
{
    __shared__ _Float16 Ash[2][128*32];
    __shared__ _Float16 Bsh[2][128*32];

    const int tid = threadIdx.x;
    const int wid = tid >> 6, lane = tid & 63;
    const int ln = lane & 15, g = lane >> 4;
    const int wrow = wid >> 1, wcol = wid & 1;
    const int m0 = blockIdx.x * 128, n0 = blockIdx.y * 128;

    // per-lane swizzled global source; linear LDS dest (tid*16B)
    const int r0 = tid >> 2, s0 = tid & 3;
    const int k8 = s0 ^ ((r0 >> 1) & 3);
    const _Float16* gA0 = Ah + (size_t)(m0 + r0)      * NE + k8*8;
    const _Float16* gA1 = Ah + (size_t)(m0 + r0 + 64) * NE + k8*8;
    const _Float16* gB0 = Bh + (size_t)(n0 + r0)      * NE + k8*8;
    const _Float16* gB1 = Bh + (size_t)(n0 + r0 + 64) * NE + k8*8;

    const int wb = (tid & ~63) * 8;            // wave-uniform LDS base (elems)
    const int xr = g ^ ((ln >> 1) & 3);

    f32x4 acc[4][4];
    #pragma unroll
    for (int i = 0; i < 4; ++i)
        #pragma unroll
        for (int j = 0; j < 4; ++j) acc[i][j] = (f32x4){0.f,0.f,0.f,0.f};

    // prologue: stage tile 0 into buf 0
    GLOAD_LDS16(gA0, Ash[0] + wb);
    GLOAD_LDS16(gA1, Ash[0] + wb + 256*8);
    GLOAD_LDS16(gB0, Bsh[0] + wb);
    GLOAD_LDS16(gB1, Bsh[0] + wb + 256*8);
    __syncthreads();

    for (int kt = 0; kt < NE; kt += 32) {
        const int cur = (kt >> 5) & 1;
        const int nxt = cur ^ 1;
        const int kn = kt + 32;
        // ds_read current fragments FIRST (starts the lgkm chain early)
        half8 af[4], bf[4];
        #pragma unroll
        for (int mf = 0; mf < 4; ++mf)
            af[mf] = *(const half8*)&Ash[cur][(wrow*64 + mf*16 + ln)*32 + xr*8];
        #pragma unroll
        for (int nf = 0; nf < 4; ++nf)
            bf[nf] = *(const half8*)&Bsh[cur][(wcol*64 + nf*16 + ln)*32 + xr*8];
        // then issue next-tile DMA (overlaps the ds_read latency)
        if (kn < NE) {
            GLOAD_LDS16(gA0 + kn, Ash[nxt] + wb);
            GLOAD_LDS16(gA1 + kn, Ash[nxt] + wb + 256*8);
            GLOAD_LDS16(gB0 + kn, Bsh[nxt] + wb);
            GLOAD_LDS16(gB1 + kn, Bsh[nxt] + wb + 256*8);
        }
        __builtin_amdgcn_s_setprio(1);
        #pragma unroll
        for (int mf = 0; mf < 4; ++mf)
            #pragma unroll
            for (int nf = 0; nf < 4; ++nf)
                acc[mf][nf] = MFMA16(af[mf], bf[nf], acc[mf][nf]);
        __builtin_amdgcn_s_setprio(0);
        __syncthreads();                       // drains next-tile loads too
    }

    const int sec = n0 >> 10;
    _Float16* dst = (sec == 0) ? Qh : (sec == 1) ? Kh : Vh;

    float cb[4], fx[4], fy[4], fz[4];
    int hh[4], dd[4];
    #pragma unroll
    for (int nf = 0; nf < 4; ++nf) {
        const int col = n0 + wcol*64 + nf*16 + ln;
        cb[nf] = bias[col];
        const int e = col & 1023;
        hh[nf] = e >> 6; dd[nf] = e & 63;
        if (sec != 2) {
            const float* fq = freqs + ((size_t)hh[nf]*NF + (dd[nf] >> 1))*3;
            fx[nf] = fq[0]; fy[nf] = fq[1]; fz[nf] = fq[2];
        }
    }
    const float sgn = (ln & 1) ? 1.0f : -1.0f;
    const float qs  = (sec == 0) ? 0.125f * 1.4426950408889634f : 1.0f;

    #pragma unroll
    for (int mf = 0; mf < 4; ++mf) {
        #pragma unroll
        for (int r = 0; r < 4; ++r) {
            const int m = m0 + wrow*64 + mf*16 + g*4 + r;
            const int b = m >> 11, t = m & 2047;
            if (sec == 2) {
                #pragma unroll
                for (int nf = 0; nf < 4; ++nf)
                    dst[((size_t)(b*NH + hh[nf])*NT + t)*ND + dd[nf]] =
                        (_Float16)(acc[mf][nf][r] + cb[nf]);
            } else {
                const float px = pos[(size_t)m*3 + 0];
                const float py = pos[(size_t)m*3 + 1];
                const float pz = pos[(size_t)m*3 + 2];
                #pragma unroll
                for (int nf = 0; nf < 4; ++nf) {
                    const float x  = acc[mf][nf][r] + cb[nf];
                    const float xo = __shfl_xor(x, 1);
                    const float ang = px*fx[nf] + py*fy[nf] + pz*fz[nf];
                    float sn, cs;
                    __sincosf(ang, &sn, &cs);
                    const float out = (x*cs + sgn*xo*sn) * qs;
                    dst[((size_t)(b*NH + hh[nf])*NT + t)*ND + dd[nf]] = (_Float16)out;
                }
            }
        }
    }
}

// ============================================================================
// Kernel 2: fp16 flash attention, 32x32x16 MFMA, swapped QK^T. (R13 exactly)
// ============================================================================
__global__ __launch_bounds__(512, 4)
void attn_mfma_kernel(const _Float16* __restrict__ Qg, const _Float16* __restrict__ Kg,
                      const _Float16* __restrict__ Vg, _Float16* __restrict__ Og)
{
    __shared__ _Float16 Ks[2][64][70];      // [buf][key][d]
    __shared__ _Float16 VsT[2][64][70];     // [buf][d][key]

    const int tid  = threadIdx.x;
    const int wid  = tid >> 6;
    const int lane = tid & 63;
    const int m31  = lane & 31;
    const int hi   = lane >> 5;
    const int bh   = blockIdx.x;
    const int qt   = blockIdx.y;
    const int b = bh >> 4, h = bh & 15;
    const _Float16* Qp = Qg + (size_t)bh * NT * ND;
    const _Float16* Kp = Kg + (size_t)bh * NT * ND;
    const _Float16* Vp = Vg + (size_t)bh * NT * ND;

    const int qrow_g = qt*256 + wid*32 + m31;

    half8 qfr[4];
    #pragma unroll
    for (int c = 0; c < 4; ++c)
        qfr[c] = *(const half8*)(Qp + (size_t)qrow_g*ND + 16*c + 8*hi);

    f32x16 o0, o1;
    #pragma unroll
    for (int e = 0; e < 16; ++e) { o0[e] = 0.f; o1[e] = 0.f; }
    float m_i = 8.0f, l_i = 0.0f;    // static bound; exact slow path guards it

    // staging geometry (512 threads)
    const int sr  = tid >> 3;            // K: key row 0..63
    const int sc0 = (tid & 7) * 8;       // K: d col base
    const int dp  = tid & 31;            // V: dword index (d = 2dp, 2dp+1)
    const int wv  = tid >> 5;            // V: key group 0..15 (4 keys each)
    const _Float16* kbase = Kp + (size_t)sr*ND + sc0;
    const _Float16* vbase = Vp + (size_t)(wv*4)*ND + 2*dp;

    half8 kv;
    unsigned int vr[4];

    #define LOADREGS(off)  do {                                              \
        kv = *(const half8*)(kbase + (size_t)(off)*ND);                      \
        _Pragma("unroll")                                                    \
        for (int j = 0; j < 4; ++j)                                          \
            vr[j] = *(const unsigned int*)(vbase + (size_t)((off) + j)*ND);  \
    } while (0)

    #define STOREBUF(bf)  do {                                               \
        *(half8*)&Ks[bf][sr][sc0] = kv;                                      \
        uint2v lod, hid;                                                     \
        lod[0] = __builtin_amdgcn_perm(vr[1], vr[0], 0x05040100u);           \
        lod[1] = __builtin_amdgcn_perm(vr[3], vr[2], 0x05040100u);           \
        hid[0] = __builtin_amdgcn_perm(vr[1], vr[0], 0x07060302u);           \
        hid[1] = __builtin_amdgcn_perm(vr[3], vr[2], 0x07060302u);           \
        *(uint2v*)&VsT[bf][2*dp][wv*4]     = lod;                            \
        *(uint2v*)&VsT[bf][2*dp + 1][wv*4] = hid;                            \
    } while (0)

    LOADREGS(0);
    STOREBUF(0);
    LOADREGS(64);

    for (int t = 0; t < 32; ++t) {
        const int cur = t & 1;
        __syncthreads();
        if (t < 31) STOREBUF(cur ^ 1);          // regs hold tile t+1
        if (t < 30) LOADREGS((t + 2) * 64);     // prefetch tile t+2

        // ---- S' = K.Q^T - m  (C initialized to -m_i) ----
        f32x16 st0, st1;
        const float mneg = -m_i;
        #pragma unroll
        for (int e = 0; e < 16; ++e) { st0[e] = mneg; st1[e] = mneg; }

        __builtin_amdgcn_s_setprio(1);
        #pragma unroll
        for (int c = 0; c < 4; ++c) {
            half8 kf0 = *(const half8*)&Ks[cur][m31][16*c + 8*hi];
            half8 kf1 = *(const half8*)&Ks[cur][32 + m31][16*c + 8*hi];
            st0 = MFMA32(kf0, qfr[c], st0);
            st1 = MFMA32(kf1, qfr[c], st1);
        }
        __builtin_amdgcn_s_setprio(0);

        // ---- p = exp2(s'), pack, fdot2 sums (no max tree on fast path) ----
        const fp16x2 ones2 = {(__fp16)1.0f, (__fp16)1.0f};
        unsigned int pku0[8], pku1[8];
        float rsA = 0.f, rsB = 0.f;
        #pragma unroll
        for (int jx = 0; jx < 8; ++jx) {
            const float pa0 = fast_exp2(st0[2*jx]);
            const float pa1 = fast_exp2(st0[2*jx + 1]);
            const float pb0 = fast_exp2(st1[2*jx]);
            const float pb1 = fast_exp2(st1[2*jx + 1]);
            const fp16x2 h2a = __builtin_amdgcn_cvt_pkrtz(pa0, pa1);
            const fp16x2 h2b = __builtin_amdgcn_cvt_pkrtz(pb0, pb1);
            pku0[jx] = __builtin_bit_cast(unsigned int, h2a);
            pku1[jx] = __builtin_bit_cast(unsigned int, h2b);
            rsA = __builtin_amdgcn_fdot2(h2a, ones2, rsA, false);
            rsB = __builtin_amdgcn_fdot2(h2b, ones2, rsB, false);
        }
        float rs = rsA + rsB;
        rs += __shfl_xor(rs, 32);

        // ---- slow path: row sum blew the bound (rs >= pmax, conservative) ----
        if (__any(rs > 256.0f)) {
            float smax = st0[0];
            #pragma unroll
            for (int e = 1; e < 16; ++e) smax = fmaxf(smax, st0[e]);
            #pragma unroll
            for (int e = 0; e < 16; ++e) smax = fmaxf(smax, st1[e]);
            smax = fmaxf(smax, __shfl_xor(smax, 32));
            const float delta = (smax > 0.0f) ? smax : 0.0f;
            const float alpha = fast_exp2(-delta);
            m_i += delta;
            l_i *= alpha;
            rs  *= alpha;
            fp16x2 am; am[0] = (__fp16)alpha; am[1] = (__fp16)alpha;
            #pragma unroll
            for (int jx = 0; jx < 8; ++jx) {
                fp16x2 p0v = __builtin_bit_cast(fp16x2, pku0[jx]) * am;
                fp16x2 p1v = __builtin_bit_cast(fp16x2, pku1[jx]) * am;
                pku0[jx] = __builtin_bit_cast(unsigned int, p0v);
                pku1[jx] = __builtin_bit_cast(unsigned int, p1v);
            }
            #pragma unroll
            for (int reg = 0; reg < 16; ++reg) {
                const int qr = (reg & 3) + 8*(reg >> 2) + 4*hi;
                const float a = __shfl(alpha, qr);
                o0[reg] *= a; o1[reg] *= a;
            }
        }
        l_i += rs;

        // ---- O += P . V : permlane32_swap assembles the A-frag ----
        __builtin_amdgcn_s_setprio(1);
        #pragma unroll
        for (int kc = 0; kc < 4; ++kc) {
            const unsigned int a0 = (kc < 2) ? pku0[4*(kc & 1) + 0] : pku1[4*(kc & 1) + 0];
            const unsigned int a1 = (kc < 2) ? pku0[4*(kc & 1) + 1] : pku1[4*(kc & 1) + 1];
            const unsigned int b0 = (kc < 2) ? pku0[4*(kc & 1) + 2] : pku1[4*(kc & 1) + 2];
            const unsigned int b1 = (kc < 2) ? pku0[4*(kc & 1) + 3] : pku1[4*(kc & 1) + 3];
            uint2v rpa = __builtin_amdgcn_permlane32_swap(a0, b0, false, false);
            uint2v rpb = __builtin_amdgcn_permlane32_swap(a1, b1, false, false);
            uint4v u;
            u[0] = rpa[0]; u[1] = rpb[0]; u[2] = rpa[1]; u[3] = rpb[1];
            const half8 pa = __builtin_bit_cast(half8, u);
            const half8 vb0 = *(const half8*)&VsT[cur][m31][16*kc + 8*hi];
            const half8 vb1 = *(const half8*)&VsT[cur][32 + m31][16*kc + 8*hi];
            o0 = MFMA32(pa, vb0, o0);
            o1 = MFMA32(pa, vb1, o1);
        }
        __builtin_amdgcn_s_setprio(0);
    }

    // ---- epilogue: normalize (l redistributed to o-row layout), write ----
    #pragma unroll
    for (int reg = 0; reg < 16; ++reg) {
        const int qr = (reg & 3) + 8*(reg >> 2) + 4*hi;
        const float lq  = __shfl(l_i, qr);
        const float inv = 1.0f / lq;
        const int qg = qt*256 + wid*32 + qr;
        _Float16* dstp = Og + ((size_t)b*NT + qg)*NE + h*ND;
        dstp[m31]      = (_Float16)(o0[reg] * inv);
        dstp[32 + m31] = (_Float16)(o1[reg] * inv);
    }
    #undef LOADREGS
    #undef STOREBUF
}

// ============================================================================
// Kernel 3: fp16 MFMA out-projection: out(f32) = Oh * Woh^T + bias. (R15)
// ============================================================================
__global__ __launch_bounds__(256)
void out_proj_mfma_kernel(const _Float16* __restrict__ Ah,
                          const _Float16* __restrict__ Bh,
                          const float* __restrict__ bias,
                          float* __restrict__ out)
{
    __shared__ _Float16 Ash[2][128*32];
    __shared__ _Float16 Bsh[2][128*32];

    const int tid = threadIdx.x;
    const int wid = tid >> 6, lane = tid & 63;
    const int ln = lane & 15, g = lane >> 4;
    const int wrow = wid >> 1, wcol = wid & 1;
    const int m0 = blockIdx.x * 128, n0 = blockIdx.y * 128;

    const int r0 = tid >> 2, s0 = tid & 3;
    const int k8 = s0 ^ ((r0 >> 1) & 3);
    const _Float16* gA0 = Ah + (size_t)(m0 + r0)      * NE + k8*8;
    const _Float16* gA1 = Ah + (size_t)(m0 + r0 + 64) * NE + k8*8;
    const _Float16* gB0 = Bh + (size_t)(n0 + r0)      * NE + k8*8;
    const _Float16* gB1 = Bh + (size_t)(n0 + r0 + 64) * NE + k8*8;

    const int wb = (tid & ~63) * 8;
    const int xr = g ^ ((ln >> 1) & 3);

    f32x4 acc[4][4];
    #pragma unroll
    for (int i = 0; i < 4; ++i)
        #pragma unroll
        for (int j = 0; j < 4; ++j) acc[i][j] = (f32x4){0.f,0.f,0.f,0.f};

    GLOAD_LDS16(gA0, Ash[0] + wb);
    GLOAD_LDS16(gA1, Ash[0] + wb + 256*8);
    GLOAD_LDS16(gB0, Bsh[0] + wb);
    GLOAD_LDS16(gB1, Bsh[0] + wb + 256*8);
    __syncthreads();

    for (int kt = 0; kt < NE; kt += 32) {
        const int cur = (kt >> 5) & 1;
        const int nxt = cur ^ 1;
        const int kn = kt + 32;
        half8 af[4], bf[4];
        #pragma unroll
        for (int mf = 0; mf < 4; ++mf)
            af[mf] = *(const half8*)&Ash[cur][(wrow*64 + mf*16 + ln)*32 + xr*8];
        #pragma unroll
        for (int nf = 0; nf < 4; ++nf)
            bf[nf] = *(const half8*)&Bsh[cur][(wcol*64 + nf*16 + ln)*32 + xr*8];
        if (kn < NE) {
            GLOAD_LDS16(gA0 + kn, Ash[nxt] + wb);
            GLOAD_LDS16(gA1 + kn, Ash[nxt] + wb + 256*8);
            GLOAD_LDS16(gB0 + kn, Bsh[nxt] + wb);
            GLOAD_LDS16(gB1 + kn, Bsh[nxt] + wb + 256*8);
        }
        __builtin_amdgcn_s_setprio(1);
        #pragma unroll
        for (int mf = 0; mf < 4; ++mf)
            #pragma unroll
            for (int nf = 0; nf < 4; ++nf)
                acc[mf][nf] = MFMA16(af[mf], bf[nf], acc[mf][nf]);
        __builtin_amdgcn_s_setprio(0);
        __syncthreads();
    }

    float cb[4];
    #pragma unroll
    for (int nf = 0; nf < 4; ++nf) cb[nf] = bias[n0 + wcol*64 + nf*16 + ln];

    #pragma unroll
    for (int mf = 0; mf < 4; ++mf)
        #pragma unroll
        for (int r = 0; r < 4; ++r) {
            const int m = m0 + wrow*64 + mf*16 + g*4 + r;
            #pragma unroll
            for (int nf = 0; nf < 4; ++nf)
                out[(size_t)m*NE + n0 + wcol*64 + nf*16 + ln] = acc[mf][nf][r] + cb[nf];
        }
}

extern "C" void kernel_launch(void* const* d_in, const int* in_sizes, int n_in,
                              void* d_out, int out_size, void* d_ws, size_t ws_size,
                              hipStream_t stream)
{
    const float* X   = (const float*)d_in[0];
    const float* pos = (const float*)d_in[1];
    const float* Wi  = (const float*)d_in[2];
    const float* bi  = (const float*)d_in[3];
    const float* Wo  = (const float*)d_in[4];
    const float* bo  = (const float*)d_in[5];
    const float* fr  = (const float*)d_in[6];
    float* out = (float*)d_out;

    _Float16* Xh  = (_Float16*)d_ws;            // 8388608
    _Float16* Wih = Xh  + 8388608;              // 3145728
    _Float16* Woh = Wih + 3145728;              // 1048576
    _Float16* Qh  = Woh + 1048576;              // 8388608
    _Float16* Kh  = Qh  + 8388608;
    _Float16* Vh  = Kh  + 8388608;
    _Float16* Oh  = Vh  + 8388608;

    cvt_kernel          <<<3072, 256, 0, stream>>>(X, Wi, Wo, Xh, Wih, Woh);
    qkv_mfma_kernel     <<<dim3(64, 24), 256, 0, stream>>>(Xh, Wih, bi, pos, fr, Qh, Kh, Vh);
    attn_mfma_kernel    <<<dim3(64, 8), 512, 0, stream>>>(Qh, Kh, Vh, Oh);
    out_proj_mfma_kernel<<<dim3(64, 8),  256, 0, stream>>>(Oh, Woh, bo, out);
}